// Round 5
// baseline (1960.969 us; speedup 1.0000x reference)
//
#include <hip/hip_runtime.h>

// ---- problem constants ----
#define NE 16
#define DD 2048
#define HH 1408
#define HSH 2816
#define TOPK 6
#define TT 4096

typedef __bf16 bf16x8 __attribute__((ext_vector_type(8)));
typedef __bf16 bf16x4 __attribute__((ext_vector_type(4)));
typedef float f32x4 __attribute__((ext_vector_type(4)));

typedef const __attribute__((address_space(1))) void gvoid_t;
typedef __attribute__((address_space(3))) void lvoid_t;

__device__ __forceinline__ void gll16(const void* g, void* l) {
  __builtin_amdgcn_global_load_lds((gvoid_t*)g, (lvoid_t*)l, 16, 0, 0);
}

// ---------------- fp32 -> bf16 convert ----------------
__global__ void k_cvt(const float* __restrict__ s, __bf16* __restrict__ d, long n4) {
  long i = (long)blockIdx.x * blockDim.x + threadIdx.x;
  long stride = (long)gridDim.x * blockDim.x;
  for (; i < n4; i += stride) {
    float4 v = ((const float4*)s)[i];
    bf16x4 o = { (__bf16)v.x, (__bf16)v.y, (__bf16)v.z, (__bf16)v.w };
    ((bf16x4*)d)[i] = o;
  }
}

// ---------------- gate: softmax + biased top-6 ----------------
__global__ __launch_bounds__(256) void k_gate(
    const float* __restrict__ x, const float* __restrict__ gw,
    const float* __restrict__ gb, float* __restrict__ cw,
    int* __restrict__ counts, int* __restrict__ lists,
    int* __restrict__ tok_e, int* __restrict__ tok_pos) {
  int t = blockIdx.x;
  int lane = threadIdx.x & 63, wave = threadIdx.x >> 6;
  __shared__ float sc[NE];
  const float* xt = x + (size_t)t * DD;
  for (int ei = 0; ei < 4; ++ei) {
    int e = wave * 4 + ei;
    const float* ge = gw + (size_t)e * DD;
    float s = 0.f;
    for (int j = 0; j < DD / 64; ++j) s += xt[lane + 64 * j] * ge[lane + 64 * j];
    for (int o = 32; o; o >>= 1) s += __shfl_xor(s, o);
    if (lane == 0) sc[e] = s;
  }
  __syncthreads();
  if (threadIdx.x == 0) {
    float p[NE], b[NE];
    float m = -1e30f;
    for (int e = 0; e < NE; ++e) m = fmaxf(m, sc[e]);
    float sum = 0.f;
    for (int e = 0; e < NE; ++e) { p[e] = expf(sc[e] - m); sum += p[e]; }
    float inv = 1.f / sum;
    for (int e = 0; e < NE; ++e) { p[e] *= inv; b[e] = p[e] + gb[e]; }
    float out[NE];
    bool used[NE];
    for (int e = 0; e < NE; ++e) { out[e] = 0.f; used[e] = false; }
    for (int k = 0; k < TOPK; ++k) {
      int best = -1; float bv = -1e30f;
      for (int e = 0; e < NE; ++e)
        if (!used[e] && b[e] > bv) { bv = b[e]; best = e; }
      used[best] = true;
      out[best] = p[best];  // ROUTE_SCALE = 1.0
      int pos = atomicAdd(&counts[best], 1);
      lists[best * TT + pos] = t;
      tok_e[t * TOPK + k] = best;
      tok_pos[t * TOPK + k] = pos;
    }
    for (int e = 0; e < NE; ++e) cw[(size_t)t * NE + e] = out[e];
  }
}

__global__ void k_offsets(const int* __restrict__ counts, int* __restrict__ offs) {
  if (threadIdx.x == 0) {
    int a = 0;
    for (int e = 0; e < NE; ++e) { offs[e] = a; a += counts[e]; }
    offs[NE] = a;
  }
}

// ---------------- persistent GEMM1 (routed): SwiGLU up-proj ----------------
// Each block OWNS one (expert, 64-col panel of W1+W3, m-half) and loops over
// m-tiles stride 2. Weight panel bytes are requested by exactly 2 co-resident
// blocks (i and i+352, same XCD since 352%8==0) -> HBM fetch ~= compulsory.
// Inner K-loop identical to the R1-verified 128x(64+64) structure.
__global__ __launch_bounds__(256, 4) void k_gemm1_p(
    const __bf16* __restrict__ xb,
    const __bf16* __restrict__ W1, const float* __restrict__ B1,
    const __bf16* __restrict__ W3, const float* __restrict__ B3,
    __bf16* __restrict__ Hout,
    const int* __restrict__ counts, const int* __restrict__ offs,
    const int* __restrict__ lists) {
  int bid = blockIdx.x;            // 0..703
  int h = bid / 352;               // m-half
  int r = bid % 352;
  int e = r / 22;
  int n0 = (r % 22) * 64;
  int count = counts[e];
  int mt = (count + 127) >> 7;
  const __bf16* W1e = W1 + (size_t)e * HH * DD;
  const __bf16* W3e = W3 + (size_t)e * HH * DD;
  const float* B1e = B1 + (size_t)e * HH;
  const float* B3e = B3 + (size_t)e * HH;
  int hbase = offs[e];
  const int* liste = lists + (size_t)e * TT;

  __shared__ __bf16 At[128 * 64];
  __shared__ __bf16 B1t[64 * 64];
  __shared__ __bf16 B3t[64 * 64];
  __shared__ int rowtok[128];

  int tid = threadIdx.x, lane = tid & 63, wave = tid >> 6;
  int wm = wave >> 1, wn = wave & 1;
  int lr8 = lane >> 3;         // 0..7 row within 8-row chunk
  int lc8 = (lane & 7) * 8;    // col start (bf16 elems)
  int fr = lane & 15;
  int fk = (lane >> 4) * 8;

  for (int mi = h; mi < mt; mi += 2) {
    int m0 = mi * 128;
    __syncthreads();  // all waves done reading previous rowtok/At
    if (tid < 128) {
      int s = m0 + tid;
      rowtok[tid] = liste[s < count ? s : count - 1];
    }
    __syncthreads();

    f32x4 acc1[4][2] = {};
    f32x4 acc3[4][2] = {};

    for (int k0 = 0; k0 < DD; k0 += 64) {
      #pragma unroll
      for (int c = 0; c < 4; ++c) {
        int br = c * 32 + wave * 8;
        int tok = rowtok[br + lr8];
        gll16(xb + (size_t)tok * DD + k0 + lc8, &At[br * 64]);
      }
      #pragma unroll
      for (int c = 0; c < 2; ++c) {
        int br = c * 32 + wave * 8;
        gll16(W1e + (size_t)(n0 + br + lr8) * DD + k0 + lc8, &B1t[br * 64]);
        gll16(W3e + (size_t)(n0 + br + lr8) * DD + k0 + lc8, &B3t[br * 64]);
      }
      __syncthreads();
      #pragma unroll
      for (int kk = 0; kk < 2; ++kk) {
        bf16x8 af[4], b1f[2], b3f[2];
        #pragma unroll
        for (int m = 0; m < 4; ++m)
          af[m] = *(const bf16x8*)&At[(wm * 64 + m * 16 + fr) * 64 + kk * 32 + fk];
        #pragma unroll
        for (int n = 0; n < 2; ++n) {
          b1f[n] = *(const bf16x8*)&B1t[(wn * 32 + n * 16 + fr) * 64 + kk * 32 + fk];
          b3f[n] = *(const bf16x8*)&B3t[(wn * 32 + n * 16 + fr) * 64 + kk * 32 + fk];
        }
        #pragma unroll
        for (int m = 0; m < 4; ++m)
          #pragma unroll
          for (int n = 0; n < 2; ++n) {
            acc1[m][n] = __builtin_amdgcn_mfma_f32_16x16x32_bf16(af[m], b1f[n], acc1[m][n], 0, 0, 0);
            acc3[m][n] = __builtin_amdgcn_mfma_f32_16x16x32_bf16(af[m], b3f[n], acc3[m][n], 0, 0, 0);
          }
      }
      __syncthreads();
    }
    // epilogue: silu(h1+b1)*(h3+b3) -> bf16
    #pragma unroll
    for (int m = 0; m < 4; ++m)
      #pragma unroll
      for (int n = 0; n < 2; ++n)
        #pragma unroll
        for (int j = 0; j < 4; ++j) {
          int rl = wm * 64 + m * 16 + (lane >> 4) * 4 + j;
          int s = m0 + rl;
          if (s < count) {
            int col = n0 + wn * 32 + n * 16 + fr;
            float h1 = acc1[m][n][j] + B1e[col];
            float h3 = acc3[m][n][j] + B3e[col];
            float v = h1 / (1.f + expf(-h1)) * h3;
            Hout[(size_t)(hbase + s) * HH + col] = (__bf16)v;
          }
        }
  }
}

// ---------------- shared-expert GEMM1 (R4 structure, unchanged) ----------------
__global__ __launch_bounds__(256, 2) void k_gemm1_s(
    const __bf16* __restrict__ xb,
    const __bf16* __restrict__ W1, const float* __restrict__ B1,
    const __bf16* __restrict__ W3, const float* __restrict__ B3,
    __bf16* __restrict__ Hout, int Hdim) {
  int m0 = blockIdx.y * 128;
  int n0 = blockIdx.x * 128;

  __shared__ __bf16 At[128 * 64];
  __shared__ __bf16 B1t[128 * 64];
  __shared__ __bf16 B3t[128 * 64];

  int tid = threadIdx.x, lane = tid & 63, wave = tid >> 6;
  int wm = wave >> 1, wn = wave & 1;
  f32x4 acc1[4][4] = {};
  f32x4 acc3[4][4] = {};
  int lr8 = lane >> 3;
  int lc8 = (lane & 7) * 8;
  int fr = lane & 15;
  int fk = (lane >> 4) * 8;

  for (int k0 = 0; k0 < DD; k0 += 64) {
    #pragma unroll
    for (int c = 0; c < 4; ++c) {
      int br = c * 32 + wave * 8;
      gll16(xb + (size_t)(m0 + br + lr8) * DD + k0 + lc8, &At[br * 64]);
      gll16(W1 + (size_t)(n0 + br + lr8) * DD + k0 + lc8, &B1t[br * 64]);
      gll16(W3 + (size_t)(n0 + br + lr8) * DD + k0 + lc8, &B3t[br * 64]);
    }
    __syncthreads();
    #pragma unroll
    for (int kk = 0; kk < 2; ++kk) {
      bf16x8 af[4], b1f[4], b3f[4];
      #pragma unroll
      for (int m = 0; m < 4; ++m)
        af[m] = *(const bf16x8*)&At[(wm * 64 + m * 16 + fr) * 64 + kk * 32 + fk];
      #pragma unroll
      for (int n = 0; n < 4; ++n) {
        b1f[n] = *(const bf16x8*)&B1t[(wn * 64 + n * 16 + fr) * 64 + kk * 32 + fk];
        b3f[n] = *(const bf16x8*)&B3t[(wn * 64 + n * 16 + fr) * 64 + kk * 32 + fk];
      }
      #pragma unroll
      for (int m = 0; m < 4; ++m)
        #pragma unroll
        for (int n = 0; n < 4; ++n) {
          acc1[m][n] = __builtin_amdgcn_mfma_f32_16x16x32_bf16(af[m], b1f[n], acc1[m][n], 0, 0, 0);
          acc3[m][n] = __builtin_amdgcn_mfma_f32_16x16x32_bf16(af[m], b3f[n], acc3[m][n], 0, 0, 0);
        }
    }
    __syncthreads();
  }
  #pragma unroll
  for (int m = 0; m < 4; ++m)
    #pragma unroll
    for (int n = 0; n < 4; ++n)
      #pragma unroll
      for (int j = 0; j < 4; ++j) {
        int rl = wm * 64 + m * 16 + (lane >> 4) * 4 + j;
        int s = m0 + rl;
        int col = n0 + wn * 64 + n * 16 + fr;
        float h1 = acc1[m][n][j] + B1[0 * Hdim + col];  // bias passed via B1 base
        float h3 = acc3[m][n][j] + B3[0 * Hdim + col];
        float v = h1 / (1.f + expf(-h1)) * h3;
        Hout[(size_t)s * Hdim + col] = (__bf16)v;
      }
}

// ---------------- persistent GEMM2 (routed): h@W2^T + b2 -> Ybuf ----------------
// Each block owns (expert, 128-col panel of W2, m-half); loops m-tiles stride 2.
// A rows are contiguous per expert (Hbuf), plain bf16 stores to Ybuf.
__global__ __launch_bounds__(256, 4) void k_gemm2_p(
    const __bf16* __restrict__ Hsrc,
    const __bf16* __restrict__ W2, const float* __restrict__ B2,
    __bf16* __restrict__ Ybuf,
    const int* __restrict__ counts, const int* __restrict__ offs) {
  int bid = blockIdx.x;            // 0..511
  int h = bid / 256;
  int r = bid % 256;
  int e = r / 16;
  int n0 = (r % 16) * 128;
  int count = counts[e];
  int mt = (count + 127) >> 7;
  int hbase = offs[e];
  const __bf16* Ae = Hsrc + (size_t)hbase * HH;
  const __bf16* W2e = W2 + (size_t)e * DD * HH;
  const float* B2e = B2 + (size_t)e * DD;

  __shared__ __bf16 At[128 * 64];
  __shared__ __bf16 Bt[128 * 64];

  int tid = threadIdx.x, lane = tid & 63, wave = tid >> 6;
  int wm = wave >> 1, wn = wave & 1;
  int lr8 = lane >> 3;
  int lc8 = (lane & 7) * 8;
  int fr = lane & 15;
  int fk = (lane >> 4) * 8;

  for (int mi = h; mi < mt; mi += 2) {
    int m0 = mi * 128;
    __syncthreads();  // all waves done with previous iteration's LDS
    f32x4 acc[4][4] = {};

    for (int k0 = 0; k0 < HH; k0 += 64) {
      #pragma unroll
      for (int c = 0; c < 4; ++c) {
        int br = c * 32 + wave * 8;
        int sr = m0 + br + lr8;
        if (sr >= count) sr = count - 1;
        gll16(Ae + (size_t)sr * HH + k0 + lc8, &At[br * 64]);
        gll16(W2e + (size_t)(n0 + br + lr8) * HH + k0 + lc8, &Bt[br * 64]);
      }
      __syncthreads();
      #pragma unroll
      for (int kk = 0; kk < 2; ++kk) {
        bf16x8 af[4], bf[4];
        #pragma unroll
        for (int m = 0; m < 4; ++m)
          af[m] = *(const bf16x8*)&At[(wm * 64 + m * 16 + fr) * 64 + kk * 32 + fk];
        #pragma unroll
        for (int n = 0; n < 4; ++n)
          bf[n] = *(const bf16x8*)&Bt[(wn * 64 + n * 16 + fr) * 64 + kk * 32 + fk];
        #pragma unroll
        for (int m = 0; m < 4; ++m)
          #pragma unroll
          for (int n = 0; n < 4; ++n)
            acc[m][n] = __builtin_amdgcn_mfma_f32_16x16x32_bf16(af[m], bf[n], acc[m][n], 0, 0, 0);
      }
      __syncthreads();
    }
    #pragma unroll
    for (int m = 0; m < 4; ++m)
      #pragma unroll
      for (int n = 0; n < 4; ++n)
        #pragma unroll
        for (int j = 0; j < 4; ++j) {
          int rl = wm * 64 + m * 16 + (lane >> 4) * 4 + j;
          int s = m0 + rl;
          if (s < count) {
            int d = n0 + wn * 64 + n * 16 + fr;
            float v = acc[m][n][j] + B2e[d];
            Ybuf[(size_t)(hbase + s) * DD + d] = (__bf16)v;
          }
        }
  }
}

// ---------------- shared-expert GEMM2 (R4 structure): -> out fp32 ----------------
__global__ __launch_bounds__(256, 2) void k_gemm2_s(
    const __bf16* __restrict__ Hsrc,
    const __bf16* __restrict__ W2, const float* __restrict__ B2,
    float* __restrict__ out) {
  int m0 = blockIdx.y * 128;
  int n0 = blockIdx.x * 128;

  __shared__ __bf16 At[128 * 64];
  __shared__ __bf16 Bt[128 * 64];

  int tid = threadIdx.x, lane = tid & 63, wave = tid >> 6;
  int wm = wave >> 1, wn = wave & 1;
  f32x4 acc[4][4] = {};
  int lr8 = lane >> 3;
  int lc8 = (lane & 7) * 8;
  int fr = lane & 15;
  int fk = (lane >> 4) * 8;

  for (int k0 = 0; k0 < HSH; k0 += 64) {
    #pragma unroll
    for (int c = 0; c < 4; ++c) {
      int br = c * 32 + wave * 8;
      gll16(Hsrc + (size_t)(m0 + br + lr8) * HSH + k0 + lc8, &At[br * 64]);
      gll16(W2 + (size_t)(n0 + br + lr8) * HSH + k0 + lc8, &Bt[br * 64]);
    }
    __syncthreads();
    #pragma unroll
    for (int kk = 0; kk < 2; ++kk) {
      bf16x8 af[4], bf[4];
      #pragma unroll
      for (int m = 0; m < 4; ++m)
        af[m] = *(const bf16x8*)&At[(wm * 64 + m * 16 + fr) * 64 + kk * 32 + fk];
      #pragma unroll
      for (int n = 0; n < 4; ++n)
        bf[n] = *(const bf16x8*)&Bt[(wn * 64 + n * 16 + fr) * 64 + kk * 32 + fk];
      #pragma unroll
      for (int m = 0; m < 4; ++m)
        #pragma unroll
        for (int n = 0; n < 4; ++n)
          acc[m][n] = __builtin_amdgcn_mfma_f32_16x16x32_bf16(af[m], bf[n], acc[m][n], 0, 0, 0);
    }
    __syncthreads();
  }
  #pragma unroll
  for (int m = 0; m < 4; ++m)
    #pragma unroll
    for (int n = 0; n < 4; ++n)
      #pragma unroll
      for (int j = 0; j < 4; ++j) {
        int rl = wm * 64 + m * 16 + (lane >> 4) * 4 + j;
        int s = m0 + rl;
        int d = n0 + wn * 64 + n * 16 + fr;
        out[(size_t)s * DD + d] = acc[m][n][j] + B2[d];
      }
}

// ---------------- combine: out[t] += sum_k cw * Ybuf[row_k] ----------------
__global__ __launch_bounds__(256) void k_combine(
    const __bf16* __restrict__ Ybuf, const float* __restrict__ cw,
    const int* __restrict__ offs, const int* __restrict__ tok_e,
    const int* __restrict__ tok_pos, float* __restrict__ out) {
  int t = blockIdx.x;
  int tid = threadIdx.x;
  __shared__ int rws[TOPK];
  __shared__ float wsh[TOPK];
  if (tid < TOPK) {
    int e = tok_e[t * TOPK + tid];
    rws[tid] = offs[e] + tok_pos[t * TOPK + tid];
    wsh[tid] = cw[(size_t)t * NE + e];
  }
  __syncthreads();
  int d0 = tid * 8;
  float a[8];
  float4 o0 = *(const float4*)&out[(size_t)t * DD + d0];
  float4 o1 = *(const float4*)&out[(size_t)t * DD + d0 + 4];
  a[0] = o0.x; a[1] = o0.y; a[2] = o0.z; a[3] = o0.w;
  a[4] = o1.x; a[5] = o1.y; a[6] = o1.z; a[7] = o1.w;
  #pragma unroll
  for (int k = 0; k < TOPK; ++k) {
    bf16x8 v = *(const bf16x8*)&Ybuf[(size_t)rws[k] * DD + d0];
    float w = wsh[k];
    #pragma unroll
    for (int j = 0; j < 8; ++j) a[j] += w * (float)v[j];
  }
  float4 r0 = { a[0], a[1], a[2], a[3] };
  float4 r1 = { a[4], a[5], a[6], a[7] };
  *(float4*)&out[(size_t)t * DD + d0] = r0;
  *(float4*)&out[(size_t)t * DD + d0 + 4] = r1;
}

// ---------------- launch ----------------
extern "C" void kernel_launch(void* const* d_in, const int* in_sizes, int n_in,
                              void* d_out, int out_size, void* d_ws, size_t ws_size,
                              hipStream_t stream) {
  const float* x      = (const float*)d_in[0];
  const float* gate_w = (const float*)d_in[1];
  const float* gate_b = (const float*)d_in[2];
  const float* w1     = (const float*)d_in[3];
  const float* b1     = (const float*)d_in[4];
  const float* w2     = (const float*)d_in[5];
  const float* b2     = (const float*)d_in[6];
  const float* w3     = (const float*)d_in[7];
  const float* b3     = (const float*)d_in[8];
  const float* ws1    = (const float*)d_in[9];
  const float* bs1    = (const float*)d_in[10];
  const float* ws2    = (const float*)d_in[11];
  const float* bs2    = (const float*)d_in[12];
  const float* ws3    = (const float*)d_in[13];
  const float* bs3    = (const float*)d_in[14];
  float* outp = (float*)d_out;

  char* ws = (char*)d_ws;
  size_t off = 0;
  auto take = [&](size_t bytes) { char* p = ws + off; off += (bytes + 255) & ~(size_t)255; return p; };
  __bf16* xb   = (__bf16*)take((size_t)TT * DD * 2);
  __bf16* w1b  = (__bf16*)take((size_t)NE * HH * DD * 2);
  __bf16* w3b  = (__bf16*)take((size_t)NE * HH * DD * 2);
  __bf16* w2b  = (__bf16*)take((size_t)NE * DD * HH * 2);
  __bf16* ws1b = (__bf16*)take((size_t)HSH * DD * 2);
  __bf16* ws3b = (__bf16*)take((size_t)HSH * DD * 2);
  __bf16* ws2b = (__bf16*)take((size_t)DD * HSH * 2);
  __bf16* Hbuf = (__bf16*)take((size_t)TT * TOPK * HH * 2);
  __bf16* Sbuf = (__bf16*)take((size_t)TT * HSH * 2);
  float*  cw   = (float*)take((size_t)TT * NE * 4);
  int*    lists  = (int*)take((size_t)NE * TT * 4);
  int*    tok_e  = (int*)take((size_t)TT * TOPK * 4);
  int*    tok_pos= (int*)take((size_t)TT * TOPK * 4);
  int*    counts = (int*)take(64);
  int*    offs   = (int*)take(128);
  // Ybuf (100.7 MB) aliases w1b (115.3 MB): w1b dead after k_gemm1_p.
  __bf16* Ybuf = w1b;

  hipMemsetAsync(counts, 0, NE * sizeof(int), stream);

  k_cvt<<<2048, 256, 0, stream>>>(x, xb, (long)TT * DD / 4);
  k_cvt<<<2048, 256, 0, stream>>>(w1, w1b, (long)NE * HH * DD / 4);
  k_cvt<<<2048, 256, 0, stream>>>(w3, w3b, (long)NE * HH * DD / 4);
  k_cvt<<<2048, 256, 0, stream>>>(w2, w2b, (long)NE * DD * HH / 4);
  k_cvt<<<2048, 256, 0, stream>>>(ws1, ws1b, (long)HSH * DD / 4);
  k_cvt<<<2048, 256, 0, stream>>>(ws3, ws3b, (long)HSH * DD / 4);
  k_cvt<<<2048, 256, 0, stream>>>(ws2, ws2b, (long)DD * HSH / 4);

  k_gate<<<TT, 256, 0, stream>>>(x, gate_w, gate_b, cw, counts, lists, tok_e, tok_pos);
  k_offsets<<<1, 64, 0, stream>>>(counts, offs);

  // routed up-proj: persistent panel-owner blocks (2 m-halves x 16 e x 22 n)
  k_gemm1_p<<<704, 256, 0, stream>>>(
      xb, w1b, b1, w3b, b3, Hbuf, counts, offs, lists);
  // shared up-proj (dense 128x128 tiles)
  k_gemm1_s<<<dim3(HSH / 128, TT / 128), 256, 0, stream>>>(
      xb, ws1b, bs1, ws3b, bs3, Sbuf, HSH);
  // routed down-proj: persistent (2 x 16 e x 16 n) -> Ybuf
  k_gemm2_p<<<512, 256, 0, stream>>>(
      Hbuf, w2b, b2, Ybuf, counts, offs);
  // shared down-proj -> out (fp32, covers every element)
  k_gemm2_s<<<dim3(DD / 128, TT / 128), 256, 0, stream>>>(
      Sbuf, ws2b, bs2, outp);
  // gather-combine routed contributions into out
  k_combine<<<TT, 256, 0, stream>>>(Ybuf, cw, offs, tok_e, tok_pos, outp);
}

// Round 6
// 1374.312 us; speedup vs baseline: 1.4269x; 1.4269x over previous
//
#include <hip/hip_runtime.h>

// ---- problem constants ----
#define NE 16
#define DD 2048
#define HH 1408
#define HSH 2816
#define TOPK 6
#define TT 4096

typedef __bf16 bf16x8 __attribute__((ext_vector_type(8)));
typedef __bf16 bf16x4 __attribute__((ext_vector_type(4)));
typedef float f32x4 __attribute__((ext_vector_type(4)));

typedef const __attribute__((address_space(1))) void gvoid_t;
typedef __attribute__((address_space(3))) void lvoid_t;

__device__ __forceinline__ void gll16(const void* g, void* l) {
  __builtin_amdgcn_global_load_lds((gvoid_t*)g, (lvoid_t*)l, 16, 0, 0);
}

// ---------------- fp32 -> bf16 convert ----------------
__global__ void k_cvt(const float* __restrict__ s, __bf16* __restrict__ d, long n4) {
  long i = (long)blockIdx.x * blockDim.x + threadIdx.x;
  long stride = (long)gridDim.x * blockDim.x;
  for (; i < n4; i += stride) {
    float4 v = ((const float4*)s)[i];
    bf16x4 o = { (__bf16)v.x, (__bf16)v.y, (__bf16)v.z, (__bf16)v.w };
    ((bf16x4*)d)[i] = o;
  }
}

// ---------------- gate: softmax + biased top-6 ----------------
__global__ __launch_bounds__(256) void k_gate(
    const float* __restrict__ x, const float* __restrict__ gw,
    const float* __restrict__ gb, float* __restrict__ cw,
    int* __restrict__ counts, int* __restrict__ lists,
    int* __restrict__ tok_e, int* __restrict__ tok_pos) {
  int t = blockIdx.x;
  int lane = threadIdx.x & 63, wave = threadIdx.x >> 6;
  __shared__ float sc[NE];
  const float* xt = x + (size_t)t * DD;
  for (int ei = 0; ei < 4; ++ei) {
    int e = wave * 4 + ei;
    const float* ge = gw + (size_t)e * DD;
    float s = 0.f;
    for (int j = 0; j < DD / 64; ++j) s += xt[lane + 64 * j] * ge[lane + 64 * j];
    for (int o = 32; o; o >>= 1) s += __shfl_xor(s, o);
    if (lane == 0) sc[e] = s;
  }
  __syncthreads();
  if (threadIdx.x == 0) {
    float p[NE], b[NE];
    float m = -1e30f;
    for (int e = 0; e < NE; ++e) m = fmaxf(m, sc[e]);
    float sum = 0.f;
    for (int e = 0; e < NE; ++e) { p[e] = expf(sc[e] - m); sum += p[e]; }
    float inv = 1.f / sum;
    for (int e = 0; e < NE; ++e) { p[e] *= inv; b[e] = p[e] + gb[e]; }
    float out[NE];
    bool used[NE];
    for (int e = 0; e < NE; ++e) { out[e] = 0.f; used[e] = false; }
    for (int k = 0; k < TOPK; ++k) {
      int best = -1; float bv = -1e30f;
      for (int e = 0; e < NE; ++e)
        if (!used[e] && b[e] > bv) { bv = b[e]; best = e; }
      used[best] = true;
      out[best] = p[best];  // ROUTE_SCALE = 1.0
      int pos = atomicAdd(&counts[best], 1);
      lists[best * TT + pos] = t;
      tok_e[t * TOPK + k] = best;
      tok_pos[t * TOPK + k] = pos;
    }
    for (int e = 0; e < NE; ++e) cw[(size_t)t * NE + e] = out[e];
  }
}

__global__ void k_offsets(const int* __restrict__ counts, int* __restrict__ offs) {
  if (threadIdx.x == 0) {
    int a = 0;
    for (int e = 0; e < NE; ++e) { offs[e] = a; a += counts[e]; }
    offs[NE] = a;
  }
}

// ---------------- GEMM1: SwiGLU (x@W1^T, x@W3^T) ----------------
// R1-proven structure: tile 128x(64+64 fused), BK=64, 4 waves (2x2),
// n-fastest grid. Change vs R1: launch_bounds (256,4) -> 4 blocks/CU
// (LDS 33KB x 4 = 133KB fits) for 2x memory-level parallelism at the
// per-K-step vmcnt drain.
template <bool GATHER>
__global__ __launch_bounds__(256, 4) void k_gemm1(
    const __bf16* __restrict__ xb,
    const __bf16* __restrict__ W1, const float* __restrict__ B1,
    const __bf16* __restrict__ W3, const float* __restrict__ B3,
    __bf16* __restrict__ Hout, int Hdim,
    const int* __restrict__ counts, const int* __restrict__ offs,
    const int* __restrict__ lists) {
  int e = blockIdx.z;
  int count = GATHER ? counts[e] : TT;
  int m0 = blockIdx.y * 128;
  if (m0 >= count) return;
  int n0 = blockIdx.x * 64;
  const __bf16* W1e = W1 + (size_t)e * Hdim * DD;
  const __bf16* W3e = W3 + (size_t)e * Hdim * DD;
  const float* B1e = B1 + (size_t)e * Hdim;
  const float* B3e = B3 + (size_t)e * Hdim;
  int hbase = GATHER ? offs[e] : 0;
  const int* liste = GATHER ? lists + (size_t)e * TT : nullptr;

  __shared__ __bf16 At[128 * 64];
  __shared__ __bf16 B1t[64 * 64];
  __shared__ __bf16 B3t[64 * 64];
  __shared__ int rowtok[128];

  int tid = threadIdx.x, lane = tid & 63, wave = tid >> 6;
  if (tid < 128) {
    int s = m0 + tid;
    rowtok[tid] = GATHER ? liste[s < count ? s : 0] : (m0 + tid);
  }
  __syncthreads();

  int wm = wave >> 1, wn = wave & 1;
  f32x4 acc1[4][2] = {};
  f32x4 acc3[4][2] = {};
  int lr8 = lane >> 3;         // 0..7 row within 8-row chunk
  int lc8 = (lane & 7) * 8;    // col start (bf16 elems)
  int fr = lane & 15;
  int fk = (lane >> 4) * 8;

  for (int k0 = 0; k0 < DD; k0 += 64) {
    #pragma unroll
    for (int c = 0; c < 4; ++c) {
      int br = c * 32 + wave * 8;
      int tok = rowtok[br + lr8];
      gll16(xb + (size_t)tok * DD + k0 + lc8, &At[br * 64]);
    }
    #pragma unroll
    for (int c = 0; c < 2; ++c) {
      int br = c * 32 + wave * 8;
      gll16(W1e + (size_t)(n0 + br + lr8) * DD + k0 + lc8, &B1t[br * 64]);
      gll16(W3e + (size_t)(n0 + br + lr8) * DD + k0 + lc8, &B3t[br * 64]);
    }
    __syncthreads();
    #pragma unroll
    for (int kk = 0; kk < 2; ++kk) {
      bf16x8 af[4], b1f[2], b3f[2];
      #pragma unroll
      for (int m = 0; m < 4; ++m)
        af[m] = *(const bf16x8*)&At[(wm * 64 + m * 16 + fr) * 64 + kk * 32 + fk];
      #pragma unroll
      for (int n = 0; n < 2; ++n) {
        b1f[n] = *(const bf16x8*)&B1t[(wn * 32 + n * 16 + fr) * 64 + kk * 32 + fk];
        b3f[n] = *(const bf16x8*)&B3t[(wn * 32 + n * 16 + fr) * 64 + kk * 32 + fk];
      }
      #pragma unroll
      for (int m = 0; m < 4; ++m)
        #pragma unroll
        for (int n = 0; n < 2; ++n) {
          acc1[m][n] = __builtin_amdgcn_mfma_f32_16x16x32_bf16(af[m], b1f[n], acc1[m][n], 0, 0, 0);
          acc3[m][n] = __builtin_amdgcn_mfma_f32_16x16x32_bf16(af[m], b3f[n], acc3[m][n], 0, 0, 0);
        }
    }
    __syncthreads();
  }
  // epilogue: silu(h1+b1)*(h3+b3) -> bf16
  #pragma unroll
  for (int m = 0; m < 4; ++m)
    #pragma unroll
    for (int n = 0; n < 2; ++n)
      #pragma unroll
      for (int j = 0; j < 4; ++j) {
        int rl = wm * 64 + m * 16 + (lane >> 4) * 4 + j;
        int s = m0 + rl;
        if (s < count) {
          int col = n0 + wn * 32 + n * 16 + fr;
          float h1 = acc1[m][n][j] + B1e[col];
          float h3 = acc3[m][n][j] + B3e[col];
          float v = h1 / (1.f + expf(-h1)) * h3;
          Hout[(size_t)(hbase + s) * Hdim + col] = (__bf16)v;
        }
      }
}

// ---------------- GEMM2: h@W2^T + b2 -> Ybuf (routed) / out (shared) ----------------
// R4 structure (128x128 tile, acc 4x4, no atomics) + launch_bounds (256,4).
template <bool GATHER>
__global__ __launch_bounds__(256, 4) void k_gemm2(
    const __bf16* __restrict__ Hsrc, int Kd,
    const __bf16* __restrict__ W2, const float* __restrict__ B2,
    float* __restrict__ out, __bf16* __restrict__ Ybuf,
    const int* __restrict__ counts, const int* __restrict__ offs) {
  int e = blockIdx.z;
  int count = GATHER ? counts[e] : TT;
  int m0 = blockIdx.y * 128;
  if (m0 >= count) return;
  int n0 = blockIdx.x * 128;
  int hbase = GATHER ? offs[e] : 0;
  const __bf16* Ae = Hsrc + (size_t)hbase * Kd;
  const __bf16* W2e = W2 + (size_t)e * DD * Kd;
  const float* B2e = B2 + (size_t)(GATHER ? e * DD : 0);

  __shared__ __bf16 At[128 * 64];
  __shared__ __bf16 Bt[128 * 64];

  int tid = threadIdx.x, lane = tid & 63, wave = tid >> 6;
  int wm = wave >> 1, wn = wave & 1;
  f32x4 acc[4][4] = {};
  int lr8 = lane >> 3;
  int lc8 = (lane & 7) * 8;
  int fr = lane & 15;
  int fk = (lane >> 4) * 8;

  for (int k0 = 0; k0 < Kd; k0 += 64) {
    #pragma unroll
    for (int c = 0; c < 4; ++c) {
      int br = c * 32 + wave * 8;
      int sr = m0 + br + lr8;
      if (sr >= count) sr = count - 1;
      gll16(Ae + (size_t)sr * Kd + k0 + lc8, &At[br * 64]);
      gll16(W2e + (size_t)(n0 + br + lr8) * Kd + k0 + lc8, &Bt[br * 64]);
    }
    __syncthreads();
    #pragma unroll
    for (int kk = 0; kk < 2; ++kk) {
      bf16x8 af[4], bf[4];
      #pragma unroll
      for (int m = 0; m < 4; ++m)
        af[m] = *(const bf16x8*)&At[(wm * 64 + m * 16 + fr) * 64 + kk * 32 + fk];
      #pragma unroll
      for (int n = 0; n < 4; ++n)
        bf[n] = *(const bf16x8*)&Bt[(wn * 64 + n * 16 + fr) * 64 + kk * 32 + fk];
      #pragma unroll
      for (int m = 0; m < 4; ++m)
        #pragma unroll
        for (int n = 0; n < 4; ++n)
          acc[m][n] = __builtin_amdgcn_mfma_f32_16x16x32_bf16(af[m], bf[n], acc[m][n], 0, 0, 0);
    }
    __syncthreads();
  }
  #pragma unroll
  for (int m = 0; m < 4; ++m)
    #pragma unroll
    for (int n = 0; n < 4; ++n)
      #pragma unroll
      for (int j = 0; j < 4; ++j) {
        int rl = wm * 64 + m * 16 + (lane >> 4) * 4 + j;
        int s = m0 + rl;
        if (s < count) {
          int d = n0 + wn * 64 + n * 16 + fr;
          float v = acc[m][n][j] + B2e[d];
          if (GATHER)
            Ybuf[(size_t)(hbase + s) * DD + d] = (__bf16)v;
          else
            out[(size_t)s * DD + d] = v;
        }
      }
}

// ---------------- combine: out[t] += sum_k cw * Ybuf[row_k] ----------------
__global__ __launch_bounds__(256) void k_combine(
    const __bf16* __restrict__ Ybuf, const float* __restrict__ cw,
    const int* __restrict__ offs, const int* __restrict__ tok_e,
    const int* __restrict__ tok_pos, float* __restrict__ out) {
  int t = blockIdx.x;
  int tid = threadIdx.x;
  __shared__ int rws[TOPK];
  __shared__ float wsh[TOPK];
  if (tid < TOPK) {
    int e = tok_e[t * TOPK + tid];
    rws[tid] = offs[e] + tok_pos[t * TOPK + tid];
    wsh[tid] = cw[(size_t)t * NE + e];
  }
  __syncthreads();
  int d0 = tid * 8;
  float a[8];
  float4 o0 = *(const float4*)&out[(size_t)t * DD + d0];
  float4 o1 = *(const float4*)&out[(size_t)t * DD + d0 + 4];
  a[0] = o0.x; a[1] = o0.y; a[2] = o0.z; a[3] = o0.w;
  a[4] = o1.x; a[5] = o1.y; a[6] = o1.z; a[7] = o1.w;
  #pragma unroll
  for (int k = 0; k < TOPK; ++k) {
    bf16x8 v = *(const bf16x8*)&Ybuf[(size_t)rws[k] * DD + d0];
    float w = wsh[k];
    #pragma unroll
    for (int j = 0; j < 8; ++j) a[j] += w * (float)v[j];
  }
  float4 r0 = { a[0], a[1], a[2], a[3] };
  float4 r1 = { a[4], a[5], a[6], a[7] };
  *(float4*)&out[(size_t)t * DD + d0] = r0;
  *(float4*)&out[(size_t)t * DD + d0 + 4] = r1;
}

// ---------------- launch ----------------
extern "C" void kernel_launch(void* const* d_in, const int* in_sizes, int n_in,
                              void* d_out, int out_size, void* d_ws, size_t ws_size,
                              hipStream_t stream) {
  const float* x      = (const float*)d_in[0];
  const float* gate_w = (const float*)d_in[1];
  const float* gate_b = (const float*)d_in[2];
  const float* w1     = (const float*)d_in[3];
  const float* b1     = (const float*)d_in[4];
  const float* w2     = (const float*)d_in[5];
  const float* b2     = (const float*)d_in[6];
  const float* w3     = (const float*)d_in[7];
  const float* b3     = (const float*)d_in[8];
  const float* ws1    = (const float*)d_in[9];
  const float* bs1    = (const float*)d_in[10];
  const float* ws2    = (const float*)d_in[11];
  const float* bs2    = (const float*)d_in[12];
  const float* ws3    = (const float*)d_in[13];
  const float* bs3    = (const float*)d_in[14];
  float* outp = (float*)d_out;

  char* ws = (char*)d_ws;
  size_t off = 0;
  auto take = [&](size_t bytes) { char* p = ws + off; off += (bytes + 255) & ~(size_t)255; return p; };
  __bf16* xb   = (__bf16*)take((size_t)TT * DD * 2);
  __bf16* w1b  = (__bf16*)take((size_t)NE * HH * DD * 2);
  __bf16* w3b  = (__bf16*)take((size_t)NE * HH * DD * 2);
  __bf16* w2b  = (__bf16*)take((size_t)NE * DD * HH * 2);
  __bf16* ws1b = (__bf16*)take((size_t)HSH * DD * 2);
  __bf16* ws3b = (__bf16*)take((size_t)HSH * DD * 2);
  __bf16* ws2b = (__bf16*)take((size_t)DD * HSH * 2);
  __bf16* Hbuf = (__bf16*)take((size_t)TT * TOPK * HH * 2);
  __bf16* Sbuf = (__bf16*)take((size_t)TT * HSH * 2);
  float*  cw   = (float*)take((size_t)TT * NE * 4);
  int*    lists  = (int*)take((size_t)NE * TT * 4);
  int*    tok_e  = (int*)take((size_t)TT * TOPK * 4);
  int*    tok_pos= (int*)take((size_t)TT * TOPK * 4);
  int*    counts = (int*)take(64);
  int*    offs   = (int*)take(128);
  // Ybuf (100.7 MB) aliases w1b (115.3 MB): w1b dead after k_gemm1<true>.
  __bf16* Ybuf = w1b;

  hipMemsetAsync(counts, 0, NE * sizeof(int), stream);

  k_cvt<<<2048, 256, 0, stream>>>(x, xb, (long)TT * DD / 4);
  k_cvt<<<2048, 256, 0, stream>>>(w1, w1b, (long)NE * HH * DD / 4);
  k_cvt<<<2048, 256, 0, stream>>>(w3, w3b, (long)NE * HH * DD / 4);
  k_cvt<<<2048, 256, 0, stream>>>(w2, w2b, (long)NE * DD * HH / 4);
  k_cvt<<<2048, 256, 0, stream>>>(ws1, ws1b, (long)HSH * DD / 4);
  k_cvt<<<2048, 256, 0, stream>>>(ws3, ws3b, (long)HSH * DD / 4);
  k_cvt<<<2048, 256, 0, stream>>>(ws2, ws2b, (long)DD * HSH / 4);

  k_gate<<<TT, 256, 0, stream>>>(x, gate_w, gate_b, cw, counts, lists, tok_e, tok_pos);
  k_offsets<<<1, 64, 0, stream>>>(counts, offs);

  // routed up-proj (R1 grid: n fastest, m middle, expert slowest)
  k_gemm1<true><<<dim3(HH / 64, TT / 128, NE), 256, 0, stream>>>(
      xb, w1b, b1, w3b, b3, Hbuf, HH, counts, offs, lists);
  // shared up-proj
  k_gemm1<false><<<dim3(HSH / 64, TT / 128, 1), 256, 0, stream>>>(
      xb, ws1b, bs1, ws3b, bs3, Sbuf, HSH, nullptr, nullptr, nullptr);
  // routed down-proj -> Ybuf (plain stores)
  k_gemm2<true><<<dim3(DD / 128, TT / 128, NE), 256, 0, stream>>>(
      Hbuf, HH, w2b, b2, nullptr, Ybuf, counts, offs);
  // shared down-proj -> out (fp32, covers every element)
  k_gemm2<false><<<dim3(DD / 128, TT / 128, 1), 256, 0, stream>>>(
      Sbuf, HSH, ws2b, bs2, outp, nullptr, nullptr, nullptr);
  // gather-combine routed contributions into out
  k_combine<<<TT, 256, 0, stream>>>(Ybuf, cw, offs, tok_e, tok_pos, outp);
}